// Round 15
// baseline (312.294 us; speedup 1.0000x reference)
//
#include <hip/hip_runtime.h>

#define NB 64       // batch
#define ND 512      // input dim
#define NM 1024     // memory slots
#define NR 4        // read heads
#define EPSF 1e-6f

typedef float f4_t __attribute__((ext_vector_type(4)));

// ---- workspace float offsets ----
static const size_t O_RM    = 9344;      // B*12 softmaxed
static const size_t O_RK    = 14272;     // B*256
static const size_t O_RSTR  = 30656;     // B*4
static const size_t O_WWGT  = 161984;    // B*M
static const size_t O_MN    = 293056;    // B*M
static const size_t O_FWDP  = 358592;    // B*2ch*M*4 = 524288, layout [(b*2+ch)*M+row][h]
static const size_t O_BWDP  = 1145024;   // B*16rg*R*M = 4,194,304

// ---- output element offsets (FLOAT32 elements) ----
static const size_t OO_RWORDS = 0;          // B*R*W   = 16384
static const size_t OO_MEM    = 16384;      // B*M*W   = 4194304
static const size_t OO_RW     = 4210688;    // B*R*M   = 262144
static const size_t OO_WWGT   = 4472832;    // B*1*M   = 65536
static const size_t OO_LINK   = 4538368;    // B*1*M*M = 67108864
static const size_t OO_PREC   = 71647232;   // B*1*M   = 65536
static const size_t OO_USAGE  = 71712768;   // B*M     = 65536

__device__ __forceinline__ float sigm(float x) { return 1.f / (1.f + expf(-x)); }
__device__ __forceinline__ float softplus_(float x) { return fmaxf(x, 0.f) + log1pf(expf(-fabsf(x))); }

// ================= K1: fused controller + rmsm + usage + alloc + writew + mem =================
__global__ __launch_bounds__(1024) void k_front(
    const float* __restrict__ x,
    const float* __restrict__ wv_w, const float* __restrict__ wv_b,
    const float* __restrict__ ev_w, const float* __restrict__ ev_b,
    const float* __restrict__ fg_w, const float* __restrict__ fg_b,
    const float* __restrict__ ag_w, const float* __restrict__ ag_b,
    const float* __restrict__ wg_w, const float* __restrict__ wg_b,
    const float* __restrict__ rm_w, const float* __restrict__ rm_b,
    const float* __restrict__ ws_w, const float* __restrict__ ws_b,
    const float* __restrict__ rs_w, const float* __restrict__ rs_b,
    const float* __restrict__ wk_w, const float* __restrict__ wk_b,
    const float* __restrict__ rk_w, const float* __restrict__ rk_b,
    const float* __restrict__ pm,  const float* __restrict__ pp,
    const float* __restrict__ pu,  const float* __restrict__ prw,
    const float* __restrict__ pww,
    float* __restrict__ wsb, float* __restrict__ out)
{
    int b = blockIdx.x, t = threadIdx.x;
    __shared__ float sv[1024];
    __shared__ int   si[1024];
    __shared__ float sp[1024];
    __shared__ float red[1024];
    __shared__ float swaw[1024];
    __shared__ float cl_wv[64], cl_ev[64], cl_wk[64], cl_fg[4], rmraw[12];
    __shared__ float cl_scal[3];   // ag, wg, wstr

    // ---- Phase A: controller linears ----
    if (t < 471) {
        int c = t;
        const float* wp; const float* bp; int O; int cl;
        int act; int dst;
        if (c < 64)       { wp = wv_w; bp = wv_b; O = 64;  cl = c;       act = 0; dst = 0; }
        else if (c < 128) { wp = ev_w; bp = ev_b; O = 64;  cl = c - 64;  act = 1; dst = 1; }
        else if (c < 132) { wp = fg_w; bp = fg_b; O = 4;   cl = c - 128; act = 1; dst = 2; }
        else if (c < 133) { wp = ag_w; bp = ag_b; O = 1;   cl = 0;       act = 1; dst = 3; }
        else if (c < 134) { wp = wg_w; bp = wg_b; O = 1;   cl = 0;       act = 1; dst = 4; }
        else if (c < 146) { wp = rm_w; bp = rm_b; O = 12;  cl = c - 134; act = 0; dst = 5; }
        else if (c < 147) { wp = ws_w; bp = ws_b; O = 1;   cl = 0;       act = 2; dst = 6; }
        else if (c < 151) { wp = rs_w; bp = rs_b; O = 4;   cl = c - 147; act = 2; dst = 7; }
        else if (c < 215) { wp = wk_w; bp = wk_b; O = 64;  cl = c - 151; act = 0; dst = 8; }
        else              { wp = rk_w; bp = rk_b; O = 256; cl = c - 215; act = 0; dst = 9; }
        float acc = bp[cl];
        const float* xb = x + b * ND;
        for (int d = 0; d < ND; ++d) acc += xb[d] * wp[d * O + cl];
        if (act == 1) acc = sigm(acc);
        else if (act == 2) acc = softplus_(acc);
        switch (dst) {
            case 0: cl_wv[cl] = acc; break;
            case 1: cl_ev[cl] = acc; break;
            case 2: cl_fg[cl] = acc; break;
            case 3: cl_scal[0] = acc; break;
            case 4: cl_scal[1] = acc; break;
            case 5: rmraw[cl] = acc; break;
            case 6: cl_scal[2] = acc; break;
            case 7: wsb[O_RSTR + b * 4 + cl] = acc; break;
            case 8: cl_wk[cl] = acc; break;
            default: wsb[O_RK + b * 256 + cl] = acc; break;
        }
    }
    __syncthreads();
    if (t < 4) {
        float a0 = rmraw[t * 3 + 0], a1 = rmraw[t * 3 + 1], a2 = rmraw[t * 3 + 2];
        float mx = fmaxf(a0, fmaxf(a1, a2));
        float e0 = expf(a0 - mx), e1 = expf(a1 - mx), e2 = expf(a2 - mx);
        float s = e0 + e1 + e2;
        float* dst = wsb + O_RM + b * 12 + t * 3;
        dst[0] = e0 / s; dst[1] = e1 / s; dst[2] = e2 / s;
    }

    // ---- Phase B: usage ----
    int m = t;
    {
        float u0 = pu[b * NM + m];
        float uaw = u0 + (1.f - u0) * pww[b * NM + m];
        float phi = 1.f;
#pragma unroll
        for (int r = 0; r < NR; r++)
            phi *= (1.f - cl_fg[r] * prw[(b * 4 + r) * NM + m]);
        float u = uaw * phi;
        out[OO_USAGE + b * NM + m] = u;
        sv[t] = EPSF + (1.0f - EPSF) * u;
        si[t] = t;
    }
    __syncthreads();

    // ---- Phase C: bitonic sort + product scan + scatter alloc ----
    for (int k = 2; k <= 1024; k <<= 1) {
        for (int j = k >> 1; j > 0; j >>= 1) {
            int ixj = t ^ j;
            if (ixj > t) {
                float a = sv[t], c = sv[ixj];
                int ia = si[t], ic = si[ixj];
                bool asc = (t & k) == 0;
                bool gt = (a > c) || (a == c && ia > ic);
                if (gt == asc) { sv[t] = c; sv[ixj] = a; si[t] = ic; si[ixj] = ia; }
            }
            __syncthreads();
        }
    }
    sp[t] = sv[t];
    __syncthreads();
    for (int off = 1; off < 1024; off <<= 1) {
        float v = sp[t];
        float o = (t >= off) ? sp[t - off] : 1.f;
        __syncthreads();
        sp[t] = v * o;
        __syncthreads();
    }
    {
        float excl = (t == 0) ? 1.f : sp[t - 1];
        swaw[si[t]] = (1.f - sv[t]) * excl;
    }
    __syncthreads();

    // ---- Phase D: write cosine + softmax + ww + precedence ----
    float kn2 = 0.f;
#pragma unroll
    for (int w = 0; w < 64; w++) { float v = cl_wk[w]; kn2 += v * v; }
    float kn = sqrtf(kn2 + EPSF);
    const float* prow = pm + ((size_t)(b * NM + m)) * 64;
    float dot = 0.f, mn2 = 0.f;
    for (int w = 0; w < 64; w++) { float pv = prow[w]; dot += cl_wk[w] * pv; mn2 += pv * pv; }
    float sim = dot / (kn * sqrtf(mn2 + EPSF)) * cl_scal[2];
    red[t] = sim; __syncthreads();
    for (int s = 512; s > 0; s >>= 1) { if (t < s) red[t] = fmaxf(red[t], red[t + s]); __syncthreads(); }
    float mx = red[0]; __syncthreads();
    float e = expf(sim - mx);
    red[t] = e; __syncthreads();
    for (int s = 512; s > 0; s >>= 1) { if (t < s) red[t] += red[t + s]; __syncthreads(); }
    float se = red[0]; __syncthreads();
    float ag = cl_scal[0], wg = cl_scal[1];
    float ww = wg * (ag * swaw[m] + (1.f - ag) * (e / se));
    wsb[O_WWGT + b * NM + m] = ww;
    out[OO_WWGT + b * NM + m] = ww;
    red[t] = ww; __syncthreads();
    for (int s = 512; s > 0; s >>= 1) { if (t < s) red[t] += red[t + s]; __syncthreads(); }
    float wwsum = red[0];
    out[OO_PREC + b * NM + m] = (1.f - wwsum) * pp[b * NM + m] + ww;

    // ---- Phase E: memory update + norms ----
    float s2 = 0.f;
    float* outr = out + OO_MEM + ((size_t)(b * NM + m)) * 64;
    for (int w = 0; w < 64; w++) {
        float val = prow[w] * (1.f - ww * cl_ev[w]) + ww * cl_wv[w];
        outr[w] = val;
        s2 += val * val;
    }
    wsb[O_MN + b * NM + m] = sqrtf(s2 + EPSF);
}

// ================= K2: fused link + fwd(2-partial) + bwd, col-halved for occupancy =================
// grid (NB, 16 rowgroups, 2 col-halves); 256 thr = 4 waves; wave owns 16 rows x 512 cols.
__global__ __launch_bounds__(256, 4) void k_linkfb(
    const float* __restrict__ pl, const float* __restrict__ pp,
    const float* __restrict__ prw, float* __restrict__ wsb, float* __restrict__ out)
{
    int b = blockIdx.x, rg = blockIdx.y, ch = blockIdx.z;
    int t = threadIdx.x, wave = t >> 6, lane = t & 63;
    int cbase = ch * 512;
    const float* wwb = wsb + O_WWGT + b * NM;
    const float* ppb = pp + b * NM;
    const float* rwb = prw + (size_t)b * 4 * NM;
    f4_t wj[2], pj[2], rwc[4][2];
#pragma unroll
    for (int s = 0; s < 2; s++) {
        int c4 = cbase + s * 256 + lane * 4;
        wj[s] = *(const f4_t*)(wwb + c4);
        pj[s] = *(const f4_t*)(ppb + c4);
#pragma unroll
        for (int h = 0; h < 4; h++)
            rwc[h][s] = *(const f4_t*)(rwb + h * NM + c4);
    }
    f4_t bacc[4][2];
#pragma unroll
    for (int h = 0; h < 4; h++)
#pragma unroll
        for (int s = 0; s < 2; s++) bacc[h][s] = (f4_t){0.f, 0.f, 0.f, 0.f};

    int rowbase = rg * 64 + wave * 16;
    f4_t vin[2];
    {
        const float* pr0 = pl + ((size_t)(b * NM + rowbase)) * NM;
#pragma unroll
        for (int s = 0; s < 2; s++)
            vin[s] = __builtin_nontemporal_load((const f4_t*)(pr0 + cbase + s * 256 + lane * 4));
    }
    for (int rr = 0; rr < 16; rr++) {
        int row = rowbase + rr;
        f4_t vc[2];
#pragma unroll
        for (int s = 0; s < 2; s++) vc[s] = vin[s];
        if (rr < 15) {
            const float* pn = pl + ((size_t)(b * NM + row + 1)) * NM;
#pragma unroll
            for (int s = 0; s < 2; s++)
                vin[s] = __builtin_nontemporal_load((const f4_t*)(pn + cbase + s * 256 + lane * 4));
        }
        float wi = wwb[row];
        float rh0 = rwb[0 * NM + row], rh1 = rwb[1 * NM + row];
        float rh2 = rwb[2 * NM + row], rh3 = rwb[3 * NM + row];
        float a = 1.f - wi;
        float* lkrow = out + OO_LINK + ((size_t)(b * NM + row)) * NM;
        float f0 = 0.f, f1 = 0.f, f2 = 0.f, f3 = 0.f;
#pragma unroll
        for (int s = 0; s < 2; s++) {
            int c4 = cbase + s * 256 + lane * 4;
            f4_t lv;
            lv.x = (a - wj[s].x) * vc[s].x + wi * pj[s].x; if (row == c4)     lv.x = 0.f;
            lv.y = (a - wj[s].y) * vc[s].y + wi * pj[s].y; if (row == c4 + 1) lv.y = 0.f;
            lv.z = (a - wj[s].z) * vc[s].z + wi * pj[s].z; if (row == c4 + 2) lv.z = 0.f;
            lv.w = (a - wj[s].w) * vc[s].w + wi * pj[s].w; if (row == c4 + 3) lv.w = 0.f;
            __builtin_nontemporal_store(lv, (f4_t*)(lkrow + c4));
            f0 += rwc[0][s].x * lv.x + rwc[0][s].y * lv.y + rwc[0][s].z * lv.z + rwc[0][s].w * lv.w;
            f1 += rwc[1][s].x * lv.x + rwc[1][s].y * lv.y + rwc[1][s].z * lv.z + rwc[1][s].w * lv.w;
            f2 += rwc[2][s].x * lv.x + rwc[2][s].y * lv.y + rwc[2][s].z * lv.z + rwc[2][s].w * lv.w;
            f3 += rwc[3][s].x * lv.x + rwc[3][s].y * lv.y + rwc[3][s].z * lv.z + rwc[3][s].w * lv.w;
            bacc[0][s].x += rh0 * lv.x; bacc[0][s].y += rh0 * lv.y; bacc[0][s].z += rh0 * lv.z; bacc[0][s].w += rh0 * lv.w;
            bacc[1][s].x += rh1 * lv.x; bacc[1][s].y += rh1 * lv.y; bacc[1][s].z += rh1 * lv.z; bacc[1][s].w += rh1 * lv.w;
            bacc[2][s].x += rh2 * lv.x; bacc[2][s].y += rh2 * lv.y; bacc[2][s].z += rh2 * lv.z; bacc[2][s].w += rh2 * lv.w;
            bacc[3][s].x += rh3 * lv.x; bacc[3][s].y += rh3 * lv.y; bacc[3][s].z += rh3 * lv.z; bacc[3][s].w += rh3 * lv.w;
        }
#pragma unroll
        for (int off = 32; off > 0; off >>= 1) {
            f0 += __shfl_down(f0, off); f1 += __shfl_down(f1, off);
            f2 += __shfl_down(f2, off); f3 += __shfl_down(f3, off);
        }
        if (lane == 0) {
            f4_t fv = (f4_t){f0, f1, f2, f3};
            *(f4_t*)(wsb + O_FWDP + ((size_t)((b * 2 + ch) * NM + row)) * 4) = fv;
        }
    }
    // block-end bwd cross-wave reduce over this col-half
    __shared__ float redb[4][512];
#pragma unroll
    for (int h = 0; h < 4; h++) {
        __syncthreads();
#pragma unroll
        for (int s = 0; s < 2; s++)
            *(f4_t*)(&redb[wave][s * 256 + lane * 4]) = bacc[h][s];
        __syncthreads();
        for (int i = t; i < 512; i += 256) {
            float sum = redb[0][i] + redb[1][i] + redb[2][i] + redb[3][i];
            wsb[O_BWDP + ((size_t)((b * 16 + rg) * 4 + h)) * NM + cbase + i] = sum;
        }
    }
}

// ================= K3: read cosine + softmax + combine (+bred +fwd-red) + read_words =================
__global__ __launch_bounds__(256) void k_readw(
    float* __restrict__ wsb, float* __restrict__ out)
{
    int br = blockIdx.x;
    int b = br >> 2, r = br & 3, t = threadIdx.x;
    __shared__ float red[256];
    __shared__ float vv[1024];
    __shared__ float red2[4][64];
    const float* rk = wsb + O_RK + (b * 4 + r) * 64;
    float kn2 = 0.f;
#pragma unroll
    for (int w = 0; w < 64; w++) { float v = rk[w]; kn2 += v * v; }
    float kn = sqrtf(kn2 + EPSF);
    float rstr = wsb[O_RSTR + b * 4 + r];
    float sim[4];
#pragma unroll
    for (int k = 0; k < 4; k++) {
        int m = t + k * 256;
        const float* row = out + OO_MEM + ((size_t)(b * NM + m)) * 64;
        float dot = 0.f;
        for (int w = 0; w < 64; w++) dot += rk[w] * row[w];
        sim[k] = dot / (kn * wsb[O_MN + b * NM + m]) * rstr;
    }
    float lm = fmaxf(fmaxf(sim[0], sim[1]), fmaxf(sim[2], sim[3]));
    red[t] = lm; __syncthreads();
    for (int s = 128; s > 0; s >>= 1) { if (t < s) red[t] = fmaxf(red[t], red[t + s]); __syncthreads(); }
    float mx = red[0]; __syncthreads();
    float e[4]; float ls = 0.f;
#pragma unroll
    for (int k = 0; k < 4; k++) { e[k] = expf(sim[k] - mx); ls += e[k]; }
    red[t] = ls; __syncthreads();
    for (int s = 128; s > 0; s >>= 1) { if (t < s) red[t] += red[t + s]; __syncthreads(); }
    float inv = 1.f / red[0];
    float bm = wsb[O_RM + b * 12 + r * 3 + 0];
    float fm = wsb[O_RM + b * 12 + r * 3 + 1];
    float cm = wsb[O_RM + b * 12 + r * 3 + 2];
#pragma unroll
    for (int k = 0; k < 4; k++) {
        int m = t + k * 256;
        float p = e[k] * inv;
        float bw = 0.f;
#pragma unroll
        for (int rg = 0; rg < 16; rg++)
            bw += wsb[O_BWDP + ((size_t)((b * 16 + rg) * 4 + r)) * NM + m];
        float fw = wsb[O_FWDP + ((size_t)((b * 2 + 0) * NM + m)) * 4 + r]
                 + wsb[O_FWDP + ((size_t)((b * 2 + 1) * NM + m)) * 4 + r];
        float v = cm * p + fm * fw + bm * bw;
        vv[m] = v;
        out[OO_RW + (size_t)(b * 4 + r) * NM + m] = v;
    }
    __syncthreads();
    int w = t & 63, chunk = t >> 6;
    const float* mem = out + OO_MEM + (size_t)b * NM * 64;
    float acc = 0.f;
    int m0 = chunk * 256;
    for (int m = m0; m < m0 + 256; m++)
        acc += vv[m] * mem[(size_t)m * 64 + w];
    red2[chunk][w] = acc;
    __syncthreads();
    if (t < 64)
        out[OO_RWORDS + br * 64 + t] = red2[0][t] + red2[1][t] + red2[2][t] + red2[3][t];
}

extern "C" void kernel_launch(void* const* d_in, const int* in_sizes, int n_in,
                              void* d_out, int out_size, void* d_ws, size_t ws_size,
                              hipStream_t stream) {
    const float* wv_w = (const float*)d_in[0];  const float* wv_b = (const float*)d_in[1];
    const float* ev_w = (const float*)d_in[2];  const float* ev_b = (const float*)d_in[3];
    const float* fg_w = (const float*)d_in[4];  const float* fg_b = (const float*)d_in[5];
    const float* ag_w = (const float*)d_in[6];  const float* ag_b = (const float*)d_in[7];
    const float* wg_w = (const float*)d_in[8];  const float* wg_b = (const float*)d_in[9];
    const float* rm_w = (const float*)d_in[10]; const float* rm_b = (const float*)d_in[11];
    const float* ws_w = (const float*)d_in[12]; const float* ws_b = (const float*)d_in[13];
    const float* rs_w = (const float*)d_in[14]; const float* rs_b = (const float*)d_in[15];
    const float* wk_w = (const float*)d_in[16]; const float* wk_b = (const float*)d_in[17];
    const float* rk_w = (const float*)d_in[18]; const float* rk_b = (const float*)d_in[19];
    const float* x   = (const float*)d_in[20];
    const float* pm  = (const float*)d_in[21];
    const float* prw = (const float*)d_in[22];
    const float* pww = (const float*)d_in[23];
    const float* pl  = (const float*)d_in[24];
    const float* pp  = (const float*)d_in[25];
    const float* pu  = (const float*)d_in[26];
    float* out = (float*)d_out;
    float* wsb = (float*)d_ws;

    k_front<<<NB, 1024, 0, stream>>>(x, wv_w, wv_b, ev_w, ev_b, fg_w, fg_b, ag_w, ag_b,
                                     wg_w, wg_b, rm_w, rm_b, ws_w, ws_b, rs_w, rs_b,
                                     wk_w, wk_b, rk_w, rk_b,
                                     pm, pp, pu, prw, pww, wsb, out);
    k_linkfb<<<dim3(NB, 16, 2), 256, 0, stream>>>(pl, pp, prw, wsb, out);
    k_readw<<<NB * NR, 256, 0, stream>>>(wsb, out);
}

// Round 16
// 247.001 us; speedup vs baseline: 1.2643x; 1.2643x over previous
//
#include <hip/hip_runtime.h>

#define NB 64       // batch
#define ND 512      // input dim
#define NM 1024     // memory slots
#define NR 4        // read heads
#define EPSF 1e-6f

typedef float f4_t __attribute__((ext_vector_type(4)));

// ---- workspace float offsets ----
static const size_t O_RM    = 9344;      // B*12 softmaxed
static const size_t O_RK    = 14272;     // B*256
static const size_t O_RSTR  = 30656;     // B*4
static const size_t O_WWGT  = 161984;    // B*M
static const size_t O_MN    = 293056;    // B*M
static const size_t O_FWDP  = 358592;    // B*2ch*M*4 = 524288, layout [(b*2+ch)*M+row][h]
static const size_t O_BWDP  = 1145024;   // B*16rg*R*M = 4,194,304

// ---- output element offsets (FLOAT32 elements) ----
static const size_t OO_RWORDS = 0;          // B*R*W   = 16384
static const size_t OO_MEM    = 16384;      // B*M*W   = 4194304
static const size_t OO_RW     = 4210688;    // B*R*M   = 262144
static const size_t OO_WWGT   = 4472832;    // B*1*M   = 65536
static const size_t OO_LINK   = 4538368;    // B*1*M*M = 67108864
static const size_t OO_PREC   = 71647232;   // B*1*M   = 65536
static const size_t OO_USAGE  = 71712768;   // B*M     = 65536

__device__ __forceinline__ float sigm(float x) { return 1.f / (1.f + expf(-x)); }
__device__ __forceinline__ float softplus_(float x) { return fmaxf(x, 0.f) + log1pf(expf(-fabsf(x))); }

// ================= K1: fused controller + rmsm + usage + alloc + writew + mem =================
__global__ __launch_bounds__(1024) void k_front(
    const float* __restrict__ x,
    const float* __restrict__ wv_w, const float* __restrict__ wv_b,
    const float* __restrict__ ev_w, const float* __restrict__ ev_b,
    const float* __restrict__ fg_w, const float* __restrict__ fg_b,
    const float* __restrict__ ag_w, const float* __restrict__ ag_b,
    const float* __restrict__ wg_w, const float* __restrict__ wg_b,
    const float* __restrict__ rm_w, const float* __restrict__ rm_b,
    const float* __restrict__ ws_w, const float* __restrict__ ws_b,
    const float* __restrict__ rs_w, const float* __restrict__ rs_b,
    const float* __restrict__ wk_w, const float* __restrict__ wk_b,
    const float* __restrict__ rk_w, const float* __restrict__ rk_b,
    const float* __restrict__ pm,  const float* __restrict__ pp,
    const float* __restrict__ pu,  const float* __restrict__ prw,
    const float* __restrict__ pww,
    float* __restrict__ wsb, float* __restrict__ out)
{
    int b = blockIdx.x, t = threadIdx.x;
    __shared__ float sv[1024];
    __shared__ int   si[1024];
    __shared__ float sp[1024];
    __shared__ float red[1024];
    __shared__ float swaw[1024];
    __shared__ float cl_wv[64], cl_ev[64], cl_wk[64], cl_fg[4], rmraw[12];
    __shared__ float cl_scal[3];   // ag, wg, wstr

    // ---- Phase A: controller linears ----
    if (t < 471) {
        int c = t;
        const float* wp; const float* bp; int O; int cl;
        int act; int dst;
        if (c < 64)       { wp = wv_w; bp = wv_b; O = 64;  cl = c;       act = 0; dst = 0; }
        else if (c < 128) { wp = ev_w; bp = ev_b; O = 64;  cl = c - 64;  act = 1; dst = 1; }
        else if (c < 132) { wp = fg_w; bp = fg_b; O = 4;   cl = c - 128; act = 1; dst = 2; }
        else if (c < 133) { wp = ag_w; bp = ag_b; O = 1;   cl = 0;       act = 1; dst = 3; }
        else if (c < 134) { wp = wg_w; bp = wg_b; O = 1;   cl = 0;       act = 1; dst = 4; }
        else if (c < 146) { wp = rm_w; bp = rm_b; O = 12;  cl = c - 134; act = 0; dst = 5; }
        else if (c < 147) { wp = ws_w; bp = ws_b; O = 1;   cl = 0;       act = 2; dst = 6; }
        else if (c < 151) { wp = rs_w; bp = rs_b; O = 4;   cl = c - 147; act = 2; dst = 7; }
        else if (c < 215) { wp = wk_w; bp = wk_b; O = 64;  cl = c - 151; act = 0; dst = 8; }
        else              { wp = rk_w; bp = rk_b; O = 256; cl = c - 215; act = 0; dst = 9; }
        float acc = bp[cl];
        const float* xb = x + b * ND;
        for (int d = 0; d < ND; ++d) acc += xb[d] * wp[d * O + cl];
        if (act == 1) acc = sigm(acc);
        else if (act == 2) acc = softplus_(acc);
        switch (dst) {
            case 0: cl_wv[cl] = acc; break;
            case 1: cl_ev[cl] = acc; break;
            case 2: cl_fg[cl] = acc; break;
            case 3: cl_scal[0] = acc; break;
            case 4: cl_scal[1] = acc; break;
            case 5: rmraw[cl] = acc; break;
            case 6: cl_scal[2] = acc; break;
            case 7: wsb[O_RSTR + b * 4 + cl] = acc; break;
            case 8: cl_wk[cl] = acc; break;
            default: wsb[O_RK + b * 256 + cl] = acc; break;
        }
    }
    __syncthreads();
    if (t < 4) {
        float a0 = rmraw[t * 3 + 0], a1 = rmraw[t * 3 + 1], a2 = rmraw[t * 3 + 2];
        float mx = fmaxf(a0, fmaxf(a1, a2));
        float e0 = expf(a0 - mx), e1 = expf(a1 - mx), e2 = expf(a2 - mx);
        float s = e0 + e1 + e2;
        float* dst = wsb + O_RM + b * 12 + t * 3;
        dst[0] = e0 / s; dst[1] = e1 / s; dst[2] = e2 / s;
    }

    // ---- Phase B: usage ----
    int m = t;
    {
        float u0 = pu[b * NM + m];
        float uaw = u0 + (1.f - u0) * pww[b * NM + m];
        float phi = 1.f;
#pragma unroll
        for (int r = 0; r < NR; r++)
            phi *= (1.f - cl_fg[r] * prw[(b * 4 + r) * NM + m]);
        float u = uaw * phi;
        out[OO_USAGE + b * NM + m] = u;
        sv[t] = EPSF + (1.0f - EPSF) * u;
        si[t] = t;
    }
    __syncthreads();

    // ---- Phase C: bitonic sort + product scan + scatter alloc ----
    for (int k = 2; k <= 1024; k <<= 1) {
        for (int j = k >> 1; j > 0; j >>= 1) {
            int ixj = t ^ j;
            if (ixj > t) {
                float a = sv[t], c = sv[ixj];
                int ia = si[t], ic = si[ixj];
                bool asc = (t & k) == 0;
                bool gt = (a > c) || (a == c && ia > ic);
                if (gt == asc) { sv[t] = c; sv[ixj] = a; si[t] = ic; si[ixj] = ia; }
            }
            __syncthreads();
        }
    }
    sp[t] = sv[t];
    __syncthreads();
    for (int off = 1; off < 1024; off <<= 1) {
        float v = sp[t];
        float o = (t >= off) ? sp[t - off] : 1.f;
        __syncthreads();
        sp[t] = v * o;
        __syncthreads();
    }
    {
        float excl = (t == 0) ? 1.f : sp[t - 1];
        swaw[si[t]] = (1.f - sv[t]) * excl;
    }
    __syncthreads();

    // ---- Phase D: write cosine + softmax + ww + precedence ----
    float kn2 = 0.f;
#pragma unroll
    for (int w = 0; w < 64; w++) { float v = cl_wk[w]; kn2 += v * v; }
    float kn = sqrtf(kn2 + EPSF);
    const float* prow = pm + ((size_t)(b * NM + m)) * 64;
    float dot = 0.f, mn2 = 0.f;
    for (int w = 0; w < 64; w++) { float pv = prow[w]; dot += cl_wk[w] * pv; mn2 += pv * pv; }
    float sim = dot / (kn * sqrtf(mn2 + EPSF)) * cl_scal[2];
    red[t] = sim; __syncthreads();
    for (int s = 512; s > 0; s >>= 1) { if (t < s) red[t] = fmaxf(red[t], red[t + s]); __syncthreads(); }
    float mx = red[0]; __syncthreads();
    float e = expf(sim - mx);
    red[t] = e; __syncthreads();
    for (int s = 512; s > 0; s >>= 1) { if (t < s) red[t] += red[t + s]; __syncthreads(); }
    float se = red[0]; __syncthreads();
    float ag = cl_scal[0], wg = cl_scal[1];
    float ww = wg * (ag * swaw[m] + (1.f - ag) * (e / se));
    wsb[O_WWGT + b * NM + m] = ww;
    out[OO_WWGT + b * NM + m] = ww;
    red[t] = ww; __syncthreads();
    for (int s = 512; s > 0; s >>= 1) { if (t < s) red[t] += red[t + s]; __syncthreads(); }
    float wwsum = red[0];
    out[OO_PREC + b * NM + m] = (1.f - wwsum) * pp[b * NM + m] + ww;

    // ---- Phase E: memory update + norms ----
    float s2 = 0.f;
    float* outr = out + OO_MEM + ((size_t)(b * NM + m)) * 64;
    for (int w = 0; w < 64; w++) {
        float val = prow[w] * (1.f - ww * cl_ev[w]) + ww * cl_wv[w];
        outr[w] = val;
        s2 += val * val;
    }
    wsb[O_MN + b * NM + m] = sqrtf(s2 + EPSF);
}

// ================= K2: fused link + fwd(2-partial) + bwd, col-halved, 3 waves/EU cap =================
// grid (NB, 16 rowgroups, 2 col-halves); 256 thr = 4 waves; wave owns 16 rows x 512 cols.
__global__ __launch_bounds__(256, 3) void k_linkfb(
    const float* __restrict__ pl, const float* __restrict__ pp,
    const float* __restrict__ prw, float* __restrict__ wsb, float* __restrict__ out)
{
    int b = blockIdx.x, rg = blockIdx.y, ch = blockIdx.z;
    int t = threadIdx.x, wave = t >> 6, lane = t & 63;
    int cbase = ch * 512;
    const float* wwb = wsb + O_WWGT + b * NM;
    const float* ppb = pp + b * NM;
    const float* rwb = prw + (size_t)b * 4 * NM;
    f4_t wj[2], pj[2], rwc[4][2];
#pragma unroll
    for (int s = 0; s < 2; s++) {
        int c4 = cbase + s * 256 + lane * 4;
        wj[s] = *(const f4_t*)(wwb + c4);
        pj[s] = *(const f4_t*)(ppb + c4);
#pragma unroll
        for (int h = 0; h < 4; h++)
            rwc[h][s] = *(const f4_t*)(rwb + h * NM + c4);
    }
    f4_t bacc[4][2];
#pragma unroll
    for (int h = 0; h < 4; h++)
#pragma unroll
        for (int s = 0; s < 2; s++) bacc[h][s] = (f4_t){0.f, 0.f, 0.f, 0.f};

    int rowbase = rg * 64 + wave * 16;
    f4_t vin[2];
    {
        const float* pr0 = pl + ((size_t)(b * NM + rowbase)) * NM;
#pragma unroll
        for (int s = 0; s < 2; s++)
            vin[s] = __builtin_nontemporal_load((const f4_t*)(pr0 + cbase + s * 256 + lane * 4));
    }
    for (int rr = 0; rr < 16; rr++) {
        int row = rowbase + rr;
        f4_t vc[2];
#pragma unroll
        for (int s = 0; s < 2; s++) vc[s] = vin[s];
        if (rr < 15) {
            const float* pn = pl + ((size_t)(b * NM + row + 1)) * NM;
#pragma unroll
            for (int s = 0; s < 2; s++)
                vin[s] = __builtin_nontemporal_load((const f4_t*)(pn + cbase + s * 256 + lane * 4));
        }
        float wi = wwb[row];
        float rh0 = rwb[0 * NM + row], rh1 = rwb[1 * NM + row];
        float rh2 = rwb[2 * NM + row], rh3 = rwb[3 * NM + row];
        float a = 1.f - wi;
        float* lkrow = out + OO_LINK + ((size_t)(b * NM + row)) * NM;
        float f0 = 0.f, f1 = 0.f, f2 = 0.f, f3 = 0.f;
#pragma unroll
        for (int s = 0; s < 2; s++) {
            int c4 = cbase + s * 256 + lane * 4;
            f4_t lv;
            lv.x = (a - wj[s].x) * vc[s].x + wi * pj[s].x; if (row == c4)     lv.x = 0.f;
            lv.y = (a - wj[s].y) * vc[s].y + wi * pj[s].y; if (row == c4 + 1) lv.y = 0.f;
            lv.z = (a - wj[s].z) * vc[s].z + wi * pj[s].z; if (row == c4 + 2) lv.z = 0.f;
            lv.w = (a - wj[s].w) * vc[s].w + wi * pj[s].w; if (row == c4 + 3) lv.w = 0.f;
            __builtin_nontemporal_store(lv, (f4_t*)(lkrow + c4));
            f0 += rwc[0][s].x * lv.x + rwc[0][s].y * lv.y + rwc[0][s].z * lv.z + rwc[0][s].w * lv.w;
            f1 += rwc[1][s].x * lv.x + rwc[1][s].y * lv.y + rwc[1][s].z * lv.z + rwc[1][s].w * lv.w;
            f2 += rwc[2][s].x * lv.x + rwc[2][s].y * lv.y + rwc[2][s].z * lv.z + rwc[2][s].w * lv.w;
            f3 += rwc[3][s].x * lv.x + rwc[3][s].y * lv.y + rwc[3][s].z * lv.z + rwc[3][s].w * lv.w;
            bacc[0][s].x += rh0 * lv.x; bacc[0][s].y += rh0 * lv.y; bacc[0][s].z += rh0 * lv.z; bacc[0][s].w += rh0 * lv.w;
            bacc[1][s].x += rh1 * lv.x; bacc[1][s].y += rh1 * lv.y; bacc[1][s].z += rh1 * lv.z; bacc[1][s].w += rh1 * lv.w;
            bacc[2][s].x += rh2 * lv.x; bacc[2][s].y += rh2 * lv.y; bacc[2][s].z += rh2 * lv.z; bacc[2][s].w += rh2 * lv.w;
            bacc[3][s].x += rh3 * lv.x; bacc[3][s].y += rh3 * lv.y; bacc[3][s].z += rh3 * lv.z; bacc[3][s].w += rh3 * lv.w;
        }
#pragma unroll
        for (int off = 32; off > 0; off >>= 1) {
            f0 += __shfl_down(f0, off); f1 += __shfl_down(f1, off);
            f2 += __shfl_down(f2, off); f3 += __shfl_down(f3, off);
        }
        if (lane == 0) {
            f4_t fv = (f4_t){f0, f1, f2, f3};
            *(f4_t*)(wsb + O_FWDP + ((size_t)((b * 2 + ch) * NM + row)) * 4) = fv;
        }
    }
    // block-end bwd cross-wave reduce over this col-half
    __shared__ float redb[4][512];
#pragma unroll
    for (int h = 0; h < 4; h++) {
        __syncthreads();
#pragma unroll
        for (int s = 0; s < 2; s++)
            *(f4_t*)(&redb[wave][s * 256 + lane * 4]) = bacc[h][s];
        __syncthreads();
        for (int i = t; i < 512; i += 256) {
            float sum = redb[0][i] + redb[1][i] + redb[2][i] + redb[3][i];
            wsb[O_BWDP + ((size_t)((b * 16 + rg) * 4 + h)) * NM + cbase + i] = sum;
        }
    }
}

// ================= K3: read cosine + softmax + combine (+bred +fwd-red) + read_words =================
__global__ __launch_bounds__(256) void k_readw(
    float* __restrict__ wsb, float* __restrict__ out)
{
    int br = blockIdx.x;
    int b = br >> 2, r = br & 3, t = threadIdx.x;
    __shared__ float red[256];
    __shared__ float vv[1024];
    __shared__ float red2[4][64];
    const float* rk = wsb + O_RK + (b * 4 + r) * 64;
    float kn2 = 0.f;
#pragma unroll
    for (int w = 0; w < 64; w++) { float v = rk[w]; kn2 += v * v; }
    float kn = sqrtf(kn2 + EPSF);
    float rstr = wsb[O_RSTR + b * 4 + r];
    float sim[4];
#pragma unroll
    for (int k = 0; k < 4; k++) {
        int m = t + k * 256;
        const float* row = out + OO_MEM + ((size_t)(b * NM + m)) * 64;
        float dot = 0.f;
        for (int w = 0; w < 64; w++) dot += rk[w] * row[w];
        sim[k] = dot / (kn * wsb[O_MN + b * NM + m]) * rstr;
    }
    float lm = fmaxf(fmaxf(sim[0], sim[1]), fmaxf(sim[2], sim[3]));
    red[t] = lm; __syncthreads();
    for (int s = 128; s > 0; s >>= 1) { if (t < s) red[t] = fmaxf(red[t], red[t + s]); __syncthreads(); }
    float mx = red[0]; __syncthreads();
    float e[4]; float ls = 0.f;
#pragma unroll
    for (int k = 0; k < 4; k++) { e[k] = expf(sim[k] - mx); ls += e[k]; }
    red[t] = ls; __syncthreads();
    for (int s = 128; s > 0; s >>= 1) { if (t < s) red[t] += red[t + s]; __syncthreads(); }
    float inv = 1.f / red[0];
    float bm = wsb[O_RM + b * 12 + r * 3 + 0];
    float fm = wsb[O_RM + b * 12 + r * 3 + 1];
    float cm = wsb[O_RM + b * 12 + r * 3 + 2];
#pragma unroll
    for (int k = 0; k < 4; k++) {
        int m = t + k * 256;
        float p = e[k] * inv;
        float bw = 0.f;
#pragma unroll
        for (int rg = 0; rg < 16; rg++)
            bw += wsb[O_BWDP + ((size_t)((b * 16 + rg) * 4 + r)) * NM + m];
        float fw = wsb[O_FWDP + ((size_t)((b * 2 + 0) * NM + m)) * 4 + r]
                 + wsb[O_FWDP + ((size_t)((b * 2 + 1) * NM + m)) * 4 + r];
        float v = cm * p + fm * fw + bm * bw;
        vv[m] = v;
        out[OO_RW + (size_t)(b * 4 + r) * NM + m] = v;
    }
    __syncthreads();
    int w = t & 63, chunk = t >> 6;
    const float* mem = out + OO_MEM + (size_t)b * NM * 64;
    float acc = 0.f;
    int m0 = chunk * 256;
    for (int m = m0; m < m0 + 256; m++)
        acc += vv[m] * mem[(size_t)m * 64 + w];
    red2[chunk][w] = acc;
    __syncthreads();
    if (t < 64)
        out[OO_RWORDS + br * 64 + t] = red2[0][t] + red2[1][t] + red2[2][t] + red2[3][t];
}

extern "C" void kernel_launch(void* const* d_in, const int* in_sizes, int n_in,
                              void* d_out, int out_size, void* d_ws, size_t ws_size,
                              hipStream_t stream) {
    const float* wv_w = (const float*)d_in[0];  const float* wv_b = (const float*)d_in[1];
    const float* ev_w = (const float*)d_in[2];  const float* ev_b = (const float*)d_in[3];
    const float* fg_w = (const float*)d_in[4];  const float* fg_b = (const float*)d_in[5];
    const float* ag_w = (const float*)d_in[6];  const float* ag_b = (const float*)d_in[7];
    const float* wg_w = (const float*)d_in[8];  const float* wg_b = (const float*)d_in[9];
    const float* rm_w = (const float*)d_in[10]; const float* rm_b = (const float*)d_in[11];
    const float* ws_w = (const float*)d_in[12]; const float* ws_b = (const float*)d_in[13];
    const float* rs_w = (const float*)d_in[14]; const float* rs_b = (const float*)d_in[15];
    const float* wk_w = (const float*)d_in[16]; const float* wk_b = (const float*)d_in[17];
    const float* rk_w = (const float*)d_in[18]; const float* rk_b = (const float*)d_in[19];
    const float* x   = (const float*)d_in[20];
    const float* pm  = (const float*)d_in[21];
    const float* prw = (const float*)d_in[22];
    const float* pww = (const float*)d_in[23];
    const float* pl  = (const float*)d_in[24];
    const float* pp  = (const float*)d_in[25];
    const float* pu  = (const float*)d_in[26];
    float* out = (float*)d_out;
    float* wsb = (float*)d_ws;

    k_front<<<NB, 1024, 0, stream>>>(x, wv_w, wv_b, ev_w, ev_b, fg_w, fg_b, ag_w, ag_b,
                                     wg_w, wg_b, rm_w, rm_b, ws_w, ws_b, rs_w, rs_b,
                                     wk_w, wk_b, rk_w, rk_b,
                                     pm, pp, pu, prw, pww, wsb, out);
    k_linkfb<<<dim3(NB, 16, 2), 256, 0, stream>>>(pl, pp, prw, wsb, out);
    k_readw<<<NB * NR, 256, 0, stream>>>(wsb, out);
}

// Round 17
// 219.514 us; speedup vs baseline: 1.4227x; 1.1252x over previous
//
#include <hip/hip_runtime.h>

#define NB 64       // batch
#define ND 512      // input dim
#define NM 1024     // memory slots
#define NR 4        // read heads
#define EPSF 1e-6f

typedef float f4_t __attribute__((ext_vector_type(4)));

// ---- workspace float offsets ----
static const size_t O_RM    = 9344;      // B*12 softmaxed
static const size_t O_RK    = 14272;     // B*256
static const size_t O_RSTR  = 30656;     // B*4
static const size_t O_WWGT  = 161984;    // B*M
static const size_t O_MN    = 293056;    // B*M
static const size_t O_FWD   = 358592;    // B*M*4, layout [b][row][h]
static const size_t O_BWDP  = 1145024;   // B*16rg*R*M = 4,194,304

// ---- output element offsets (FLOAT32 elements) ----
static const size_t OO_RWORDS = 0;          // B*R*W   = 16384
static const size_t OO_MEM    = 16384;      // B*M*W   = 4194304
static const size_t OO_RW     = 4210688;    // B*R*M   = 262144
static const size_t OO_WWGT   = 4472832;    // B*1*M   = 65536
static const size_t OO_LINK   = 4538368;    // B*1*M*M = 67108864
static const size_t OO_PREC   = 71647232;   // B*1*M   = 65536
static const size_t OO_USAGE  = 71712768;   // B*M     = 65536

__device__ __forceinline__ float sigm(float x) { return 1.f / (1.f + expf(-x)); }
__device__ __forceinline__ float softplus_(float x) { return fmaxf(x, 0.f) + log1pf(expf(-fabsf(x))); }

// ================= K1: fused controller + rmsm + usage + alloc + writew + mem =================
__global__ __launch_bounds__(1024) void k_front(
    const float* __restrict__ x,
    const float* __restrict__ wv_w, const float* __restrict__ wv_b,
    const float* __restrict__ ev_w, const float* __restrict__ ev_b,
    const float* __restrict__ fg_w, const float* __restrict__ fg_b,
    const float* __restrict__ ag_w, const float* __restrict__ ag_b,
    const float* __restrict__ wg_w, const float* __restrict__ wg_b,
    const float* __restrict__ rm_w, const float* __restrict__ rm_b,
    const float* __restrict__ ws_w, const float* __restrict__ ws_b,
    const float* __restrict__ rs_w, const float* __restrict__ rs_b,
    const float* __restrict__ wk_w, const float* __restrict__ wk_b,
    const float* __restrict__ rk_w, const float* __restrict__ rk_b,
    const float* __restrict__ pm,  const float* __restrict__ pp,
    const float* __restrict__ pu,  const float* __restrict__ prw,
    const float* __restrict__ pww,
    float* __restrict__ wsb, float* __restrict__ out)
{
    int b = blockIdx.x, t = threadIdx.x;
    __shared__ float sv[1024];
    __shared__ int   si[1024];
    __shared__ float sp[1024];
    __shared__ float red[1024];
    __shared__ float swaw[1024];
    __shared__ float cl_wv[64], cl_ev[64], cl_wk[64], cl_fg[4], rmraw[12];
    __shared__ float cl_scal[3];   // ag, wg, wstr

    // ---- Phase A: controller linears ----
    if (t < 471) {
        int c = t;
        const float* wp; const float* bp; int O; int cl;
        int act; int dst;
        if (c < 64)       { wp = wv_w; bp = wv_b; O = 64;  cl = c;       act = 0; dst = 0; }
        else if (c < 128) { wp = ev_w; bp = ev_b; O = 64;  cl = c - 64;  act = 1; dst = 1; }
        else if (c < 132) { wp = fg_w; bp = fg_b; O = 4;   cl = c - 128; act = 1; dst = 2; }
        else if (c < 133) { wp = ag_w; bp = ag_b; O = 1;   cl = 0;       act = 1; dst = 3; }
        else if (c < 134) { wp = wg_w; bp = wg_b; O = 1;   cl = 0;       act = 1; dst = 4; }
        else if (c < 146) { wp = rm_w; bp = rm_b; O = 12;  cl = c - 134; act = 0; dst = 5; }
        else if (c < 147) { wp = ws_w; bp = ws_b; O = 1;   cl = 0;       act = 2; dst = 6; }
        else if (c < 151) { wp = rs_w; bp = rs_b; O = 4;   cl = c - 147; act = 2; dst = 7; }
        else if (c < 215) { wp = wk_w; bp = wk_b; O = 64;  cl = c - 151; act = 0; dst = 8; }
        else              { wp = rk_w; bp = rk_b; O = 256; cl = c - 215; act = 0; dst = 9; }
        float acc = bp[cl];
        const float* xb = x + b * ND;
        for (int d = 0; d < ND; ++d) acc += xb[d] * wp[d * O + cl];
        if (act == 1) acc = sigm(acc);
        else if (act == 2) acc = softplus_(acc);
        switch (dst) {
            case 0: cl_wv[cl] = acc; break;
            case 1: cl_ev[cl] = acc; break;
            case 2: cl_fg[cl] = acc; break;
            case 3: cl_scal[0] = acc; break;
            case 4: cl_scal[1] = acc; break;
            case 5: rmraw[cl] = acc; break;
            case 6: cl_scal[2] = acc; break;
            case 7: wsb[O_RSTR + b * 4 + cl] = acc; break;
            case 8: cl_wk[cl] = acc; break;
            default: wsb[O_RK + b * 256 + cl] = acc; break;
        }
    }
    __syncthreads();
    if (t < 4) {
        float a0 = rmraw[t * 3 + 0], a1 = rmraw[t * 3 + 1], a2 = rmraw[t * 3 + 2];
        float mx = fmaxf(a0, fmaxf(a1, a2));
        float e0 = expf(a0 - mx), e1 = expf(a1 - mx), e2 = expf(a2 - mx);
        float s = e0 + e1 + e2;
        float* dst = wsb + O_RM + b * 12 + t * 3;
        dst[0] = e0 / s; dst[1] = e1 / s; dst[2] = e2 / s;
    }

    // ---- Phase B: usage ----
    int m = t;
    {
        float u0 = pu[b * NM + m];
        float uaw = u0 + (1.f - u0) * pww[b * NM + m];
        float phi = 1.f;
#pragma unroll
        for (int r = 0; r < NR; r++)
            phi *= (1.f - cl_fg[r] * prw[(b * 4 + r) * NM + m]);
        float u = uaw * phi;
        out[OO_USAGE + b * NM + m] = u;
        sv[t] = EPSF + (1.0f - EPSF) * u;
        si[t] = t;
    }
    __syncthreads();

    // ---- Phase C: bitonic sort + product scan + scatter alloc ----
    for (int k = 2; k <= 1024; k <<= 1) {
        for (int j = k >> 1; j > 0; j >>= 1) {
            int ixj = t ^ j;
            if (ixj > t) {
                float a = sv[t], c = sv[ixj];
                int ia = si[t], ic = si[ixj];
                bool asc = (t & k) == 0;
                bool gt = (a > c) || (a == c && ia > ic);
                if (gt == asc) { sv[t] = c; sv[ixj] = a; si[t] = ic; si[ixj] = ia; }
            }
            __syncthreads();
        }
    }
    sp[t] = sv[t];
    __syncthreads();
    for (int off = 1; off < 1024; off <<= 1) {
        float v = sp[t];
        float o = (t >= off) ? sp[t - off] : 1.f;
        __syncthreads();
        sp[t] = v * o;
        __syncthreads();
    }
    {
        float excl = (t == 0) ? 1.f : sp[t - 1];
        swaw[si[t]] = (1.f - sv[t]) * excl;
    }
    __syncthreads();

    // ---- Phase D: write cosine + softmax + ww + precedence ----
    float kn2 = 0.f;
#pragma unroll
    for (int w = 0; w < 64; w++) { float v = cl_wk[w]; kn2 += v * v; }
    float kn = sqrtf(kn2 + EPSF);
    const float* prow = pm + ((size_t)(b * NM + m)) * 64;
    float dot = 0.f, mn2 = 0.f;
    for (int w = 0; w < 64; w++) { float pv = prow[w]; dot += cl_wk[w] * pv; mn2 += pv * pv; }
    float sim = dot / (kn * sqrtf(mn2 + EPSF)) * cl_scal[2];
    red[t] = sim; __syncthreads();
    for (int s = 512; s > 0; s >>= 1) { if (t < s) red[t] = fmaxf(red[t], red[t + s]); __syncthreads(); }
    float mx = red[0]; __syncthreads();
    float e = expf(sim - mx);
    red[t] = e; __syncthreads();
    for (int s = 512; s > 0; s >>= 1) { if (t < s) red[t] += red[t + s]; __syncthreads(); }
    float se = red[0]; __syncthreads();
    float ag = cl_scal[0], wg = cl_scal[1];
    float ww = wg * (ag * swaw[m] + (1.f - ag) * (e / se));
    wsb[O_WWGT + b * NM + m] = ww;
    out[OO_WWGT + b * NM + m] = ww;
    red[t] = ww; __syncthreads();
    for (int s = 512; s > 0; s >>= 1) { if (t < s) red[t] += red[t + s]; __syncthreads(); }
    float wwsum = red[0];
    out[OO_PREC + b * NM + m] = (1.f - wwsum) * pp[b * NM + m] + ww;

    // ---- Phase E: memory update + norms ----
    float s2 = 0.f;
    float* outr = out + OO_MEM + ((size_t)(b * NM + m)) * 64;
    for (int w = 0; w < 64; w++) {
        float val = prow[w] * (1.f - ww * cl_ev[w]) + ww * cl_wv[w];
        outr[w] = val;
        s2 += val * val;
    }
    wsb[O_MN + b * NM + m] = sqrtf(s2 + EPSF);
}

// ================= K2: fused link + fwd + bwd, wave-per-row-strip, nontemporal stream =================
__global__ __launch_bounds__(256) void k_linkfb(
    const float* __restrict__ pl, const float* __restrict__ pp,
    const float* __restrict__ prw, float* __restrict__ wsb, float* __restrict__ out)
{
    int b = blockIdx.x, rg = blockIdx.y;
    int t = threadIdx.x, wave = t >> 6, lane = t & 63;
    const float* wwb = wsb + O_WWGT + b * NM;
    const float* ppb = pp + b * NM;
    const float* rwb = prw + (size_t)b * 4 * NM;
    f4_t wj[4], pj[4], rwc[4][4];
#pragma unroll
    for (int s = 0; s < 4; s++) {
        int c4 = s * 256 + lane * 4;
        wj[s] = *(const f4_t*)(wwb + c4);
        pj[s] = *(const f4_t*)(ppb + c4);
#pragma unroll
        for (int h = 0; h < 4; h++)
            rwc[h][s] = *(const f4_t*)(rwb + h * NM + c4);
    }
    f4_t bacc[4][4];
#pragma unroll
    for (int h = 0; h < 4; h++)
#pragma unroll
        for (int s = 0; s < 4; s++) bacc[h][s] = (f4_t){0.f, 0.f, 0.f, 0.f};

    int rowbase = rg * 64 + wave * 16;
    f4_t vin[4];
    {
        const float* pr0 = pl + ((size_t)(b * NM + rowbase)) * NM;
#pragma unroll
        for (int s = 0; s < 4; s++)
            vin[s] = __builtin_nontemporal_load((const f4_t*)(pr0 + s * 256 + lane * 4));
    }
    for (int rr = 0; rr < 16; rr++) {
        int row = rowbase + rr;
        f4_t vc[4];
#pragma unroll
        for (int s = 0; s < 4; s++) vc[s] = vin[s];
        if (rr < 15) {
            const float* pn = pl + ((size_t)(b * NM + row + 1)) * NM;
#pragma unroll
            for (int s = 0; s < 4; s++)
                vin[s] = __builtin_nontemporal_load((const f4_t*)(pn + s * 256 + lane * 4));
        }
        float wi = wwb[row];
        float rh0 = rwb[0 * NM + row], rh1 = rwb[1 * NM + row];
        float rh2 = rwb[2 * NM + row], rh3 = rwb[3 * NM + row];
        float a = 1.f - wi;
        float* lkrow = out + OO_LINK + ((size_t)(b * NM + row)) * NM;
        float f0 = 0.f, f1 = 0.f, f2 = 0.f, f3 = 0.f;
#pragma unroll
        for (int s = 0; s < 4; s++) {
            int c4 = s * 256 + lane * 4;
            f4_t lv;
            lv.x = (a - wj[s].x) * vc[s].x + wi * pj[s].x; if (row == c4)     lv.x = 0.f;
            lv.y = (a - wj[s].y) * vc[s].y + wi * pj[s].y; if (row == c4 + 1) lv.y = 0.f;
            lv.z = (a - wj[s].z) * vc[s].z + wi * pj[s].z; if (row == c4 + 2) lv.z = 0.f;
            lv.w = (a - wj[s].w) * vc[s].w + wi * pj[s].w; if (row == c4 + 3) lv.w = 0.f;
            __builtin_nontemporal_store(lv, (f4_t*)(lkrow + c4));
            f0 += rwc[0][s].x * lv.x + rwc[0][s].y * lv.y + rwc[0][s].z * lv.z + rwc[0][s].w * lv.w;
            f1 += rwc[1][s].x * lv.x + rwc[1][s].y * lv.y + rwc[1][s].z * lv.z + rwc[1][s].w * lv.w;
            f2 += rwc[2][s].x * lv.x + rwc[2][s].y * lv.y + rwc[2][s].z * lv.z + rwc[2][s].w * lv.w;
            f3 += rwc[3][s].x * lv.x + rwc[3][s].y * lv.y + rwc[3][s].z * lv.z + rwc[3][s].w * lv.w;
            bacc[0][s].x += rh0 * lv.x; bacc[0][s].y += rh0 * lv.y; bacc[0][s].z += rh0 * lv.z; bacc[0][s].w += rh0 * lv.w;
            bacc[1][s].x += rh1 * lv.x; bacc[1][s].y += rh1 * lv.y; bacc[1][s].z += rh1 * lv.z; bacc[1][s].w += rh1 * lv.w;
            bacc[2][s].x += rh2 * lv.x; bacc[2][s].y += rh2 * lv.y; bacc[2][s].z += rh2 * lv.z; bacc[2][s].w += rh2 * lv.w;
            bacc[3][s].x += rh3 * lv.x; bacc[3][s].y += rh3 * lv.y; bacc[3][s].z += rh3 * lv.z; bacc[3][s].w += rh3 * lv.w;
        }
#pragma unroll
        for (int off = 32; off > 0; off >>= 1) {
            f0 += __shfl_down(f0, off); f1 += __shfl_down(f1, off);
            f2 += __shfl_down(f2, off); f3 += __shfl_down(f3, off);
        }
        if (lane == 0) {
            f4_t fv = (f4_t){f0, f1, f2, f3};
            *(f4_t*)(wsb + O_FWD + (size_t)(b * NM + row) * 4) = fv;
        }
    }
    __shared__ float redb[4][1024];
#pragma unroll
    for (int h = 0; h < 4; h++) {
        __syncthreads();
#pragma unroll
        for (int s = 0; s < 4; s++)
            *(f4_t*)(&redb[wave][s * 256 + lane * 4]) = bacc[h][s];
        __syncthreads();
        for (int i = t; i < 1024; i += 256) {
            float sum = redb[0][i] + redb[1][i] + redb[2][i] + redb[3][i];
            wsb[O_BWDP + ((size_t)((b * 16 + rg) * 4 + h)) * NM + i] = sum;
        }
    }
}

// ================= K3: read cosine + softmax + combine (+bred) + read_words =================
__global__ __launch_bounds__(256) void k_readw(
    float* __restrict__ wsb, float* __restrict__ out)
{
    int br = blockIdx.x;
    int b = br >> 2, r = br & 3, t = threadIdx.x;
    __shared__ float red[256];
    __shared__ float vv[1024];
    __shared__ float red2[4][64];
    const float* rk = wsb + O_RK + (b * 4 + r) * 64;
    float kn2 = 0.f;
#pragma unroll
    for (int w = 0; w < 64; w++) { float v = rk[w]; kn2 += v * v; }
    float kn = sqrtf(kn2 + EPSF);
    float rstr = wsb[O_RSTR + b * 4 + r];
    float sim[4];
#pragma unroll
    for (int k = 0; k < 4; k++) {
        int m = t + k * 256;
        const float* row = out + OO_MEM + ((size_t)(b * NM + m)) * 64;
        float dot = 0.f;
        for (int w = 0; w < 64; w++) dot += rk[w] * row[w];
        sim[k] = dot / (kn * wsb[O_MN + b * NM + m]) * rstr;
    }
    float lm = fmaxf(fmaxf(sim[0], sim[1]), fmaxf(sim[2], sim[3]));
    red[t] = lm; __syncthreads();
    for (int s = 128; s > 0; s >>= 1) { if (t < s) red[t] = fmaxf(red[t], red[t + s]); __syncthreads(); }
    float mx = red[0]; __syncthreads();
    float e[4]; float ls = 0.f;
#pragma unroll
    for (int k = 0; k < 4; k++) { e[k] = expf(sim[k] - mx); ls += e[k]; }
    red[t] = ls; __syncthreads();
    for (int s = 128; s > 0; s >>= 1) { if (t < s) red[t] += red[t + s]; __syncthreads(); }
    float inv = 1.f / red[0];
    float bm = wsb[O_RM + b * 12 + r * 3 + 0];
    float fm = wsb[O_RM + b * 12 + r * 3 + 1];
    float cm = wsb[O_RM + b * 12 + r * 3 + 2];
#pragma unroll
    for (int k = 0; k < 4; k++) {
        int m = t + k * 256;
        float p = e[k] * inv;
        float bw = 0.f;
#pragma unroll
        for (int rg = 0; rg < 16; rg++)
            bw += wsb[O_BWDP + ((size_t)((b * 16 + rg) * 4 + r)) * NM + m];
        float fw = wsb[O_FWD + (size_t)(b * NM + m) * 4 + r];
        float v = cm * p + fm * fw + bm * bw;
        vv[m] = v;
        out[OO_RW + (size_t)(b * 4 + r) * NM + m] = v;
    }
    __syncthreads();
    int w = t & 63, chunk = t >> 6;
    const float* mem = out + OO_MEM + (size_t)b * NM * 64;
    float acc = 0.f;
    int m0 = chunk * 256;
    for (int m = m0; m < m0 + 256; m++)
        acc += vv[m] * mem[(size_t)m * 64 + w];
    red2[chunk][w] = acc;
    __syncthreads();
    if (t < 64)
        out[OO_RWORDS + br * 64 + t] = red2[0][t] + red2[1][t] + red2[2][t] + red2[3][t];
}

extern "C" void kernel_launch(void* const* d_in, const int* in_sizes, int n_in,
                              void* d_out, int out_size, void* d_ws, size_t ws_size,
                              hipStream_t stream) {
    const float* wv_w = (const float*)d_in[0];  const float* wv_b = (const float*)d_in[1];
    const float* ev_w = (const float*)d_in[2];  const float* ev_b = (const float*)d_in[3];
    const float* fg_w = (const float*)d_in[4];  const float* fg_b = (const float*)d_in[5];
    const float* ag_w = (const float*)d_in[6];  const float* ag_b = (const float*)d_in[7];
    const float* wg_w = (const float*)d_in[8];  const float* wg_b = (const float*)d_in[9];
    const float* rm_w = (const float*)d_in[10]; const float* rm_b = (const float*)d_in[11];
    const float* ws_w = (const float*)d_in[12]; const float* ws_b = (const float*)d_in[13];
    const float* rs_w = (const float*)d_in[14]; const float* rs_b = (const float*)d_in[15];
    const float* wk_w = (const float*)d_in[16]; const float* wk_b = (const float*)d_in[17];
    const float* rk_w = (const float*)d_in[18]; const float* rk_b = (const float*)d_in[19];
    const float* x   = (const float*)d_in[20];
    const float* pm  = (const float*)d_in[21];
    const float* prw = (const float*)d_in[22];
    const float* pww = (const float*)d_in[23];
    const float* pl  = (const float*)d_in[24];
    const float* pp  = (const float*)d_in[25];
    const float* pu  = (const float*)d_in[26];
    float* out = (float*)d_out;
    float* wsb = (float*)d_ws;

    k_front<<<NB, 1024, 0, stream>>>(x, wv_w, wv_b, ev_w, ev_b, fg_w, fg_b, ag_w, ag_b,
                                     wg_w, wg_b, rm_w, rm_b, ws_w, ws_b, rs_w, rs_b,
                                     wk_w, wk_b, rk_w, rk_b,
                                     pm, pp, pu, prw, pww, wsb, out);
    k_linkfb<<<dim3(NB, 16), 256, 0, stream>>>(pl, pp, prw, wsb, out);
    k_readw<<<NB * NR, 256, 0, stream>>>(wsb, out);
}

// Round 18
// 208.922 us; speedup vs baseline: 1.4948x; 1.0507x over previous
//
#include <hip/hip_runtime.h>

#define NB 64       // batch
#define ND 512      // input dim
#define NM 1024     // memory slots
#define NR 4        // read heads
#define EPSF 1e-6f

typedef float f4_t __attribute__((ext_vector_type(4)));

// ---- workspace float offsets ----
static const size_t O_RM    = 9344;      // B*12 softmaxed
static const size_t O_RK    = 14272;     // B*256
static const size_t O_RSTR  = 30656;     // B*4
static const size_t O_WWGT  = 161984;    // B*M
static const size_t O_MN    = 293056;    // B*M
static const size_t O_FWD   = 358592;    // B*M*4, layout [b][row][h]
static const size_t O_BWDP  = 1145024;   // B*16rg*R*M = 4,194,304

// ---- output element offsets (FLOAT32 elements) ----
static const size_t OO_RWORDS = 0;          // B*R*W   = 16384
static const size_t OO_MEM    = 16384;      // B*M*W   = 4194304
static const size_t OO_RW     = 4210688;    // B*R*M   = 262144
static const size_t OO_WWGT   = 4472832;    // B*1*M   = 65536
static const size_t OO_LINK   = 4538368;    // B*1*M*M = 67108864
static const size_t OO_PREC   = 71647232;   // B*1*M   = 65536
static const size_t OO_USAGE  = 71712768;   // B*M     = 65536

__device__ __forceinline__ float sigm(float x) { return 1.f / (1.f + expf(-x)); }
__device__ __forceinline__ float softplus_(float x) { return fmaxf(x, 0.f) + log1pf(expf(-fabsf(x))); }

// ================= K1: fused controller + rmsm + usage + alloc + writew + mem =================
__global__ __launch_bounds__(1024) void k_front(
    const float* __restrict__ x,
    const float* __restrict__ wv_w, const float* __restrict__ wv_b,
    const float* __restrict__ ev_w, const float* __restrict__ ev_b,
    const float* __restrict__ fg_w, const float* __restrict__ fg_b,
    const float* __restrict__ ag_w, const float* __restrict__ ag_b,
    const float* __restrict__ wg_w, const float* __restrict__ wg_b,
    const float* __restrict__ rm_w, const float* __restrict__ rm_b,
    const float* __restrict__ ws_w, const float* __restrict__ ws_b,
    const float* __restrict__ rs_w, const float* __restrict__ rs_b,
    const float* __restrict__ wk_w, const float* __restrict__ wk_b,
    const float* __restrict__ rk_w, const float* __restrict__ rk_b,
    const float* __restrict__ pm,  const float* __restrict__ pp,
    const float* __restrict__ pu,  const float* __restrict__ prw,
    const float* __restrict__ pww,
    float* __restrict__ wsb, float* __restrict__ out)
{
    int b = blockIdx.x, t = threadIdx.x;
    __shared__ float sv[1024];
    __shared__ int   si[1024];
    __shared__ float sp[1024];
    __shared__ float red[1024];
    __shared__ float swaw[1024];
    __shared__ float cl_wv[64], cl_ev[64], cl_wk[64], cl_fg[4], rmraw[12];
    __shared__ float cl_scal[3];   // ag, wg, wstr

    // ---- Phase A: controller linears ----
    if (t < 471) {
        int c = t;
        const float* wp; const float* bp; int O; int cl;
        int act; int dst;
        if (c < 64)       { wp = wv_w; bp = wv_b; O = 64;  cl = c;       act = 0; dst = 0; }
        else if (c < 128) { wp = ev_w; bp = ev_b; O = 64;  cl = c - 64;  act = 1; dst = 1; }
        else if (c < 132) { wp = fg_w; bp = fg_b; O = 4;   cl = c - 128; act = 1; dst = 2; }
        else if (c < 133) { wp = ag_w; bp = ag_b; O = 1;   cl = 0;       act = 1; dst = 3; }
        else if (c < 134) { wp = wg_w; bp = wg_b; O = 1;   cl = 0;       act = 1; dst = 4; }
        else if (c < 146) { wp = rm_w; bp = rm_b; O = 12;  cl = c - 134; act = 0; dst = 5; }
        else if (c < 147) { wp = ws_w; bp = ws_b; O = 1;   cl = 0;       act = 2; dst = 6; }
        else if (c < 151) { wp = rs_w; bp = rs_b; O = 4;   cl = c - 147; act = 2; dst = 7; }
        else if (c < 215) { wp = wk_w; bp = wk_b; O = 64;  cl = c - 151; act = 0; dst = 8; }
        else              { wp = rk_w; bp = rk_b; O = 256; cl = c - 215; act = 0; dst = 9; }
        float acc = bp[cl];
        const float* xb = x + b * ND;
        for (int d = 0; d < ND; ++d) acc += xb[d] * wp[d * O + cl];
        if (act == 1) acc = sigm(acc);
        else if (act == 2) acc = softplus_(acc);
        switch (dst) {
            case 0: cl_wv[cl] = acc; break;
            case 1: cl_ev[cl] = acc; break;
            case 2: cl_fg[cl] = acc; break;
            case 3: cl_scal[0] = acc; break;
            case 4: cl_scal[1] = acc; break;
            case 5: rmraw[cl] = acc; break;
            case 6: cl_scal[2] = acc; break;
            case 7: wsb[O_RSTR + b * 4 + cl] = acc; break;
            case 8: cl_wk[cl] = acc; break;
            default: wsb[O_RK + b * 256 + cl] = acc; break;
        }
    }
    __syncthreads();
    if (t < 4) {
        float a0 = rmraw[t * 3 + 0], a1 = rmraw[t * 3 + 1], a2 = rmraw[t * 3 + 2];
        float mx = fmaxf(a0, fmaxf(a1, a2));
        float e0 = expf(a0 - mx), e1 = expf(a1 - mx), e2 = expf(a2 - mx);
        float s = e0 + e1 + e2;
        float* dst = wsb + O_RM + b * 12 + t * 3;
        dst[0] = e0 / s; dst[1] = e1 / s; dst[2] = e2 / s;
    }

    // ---- Phase B: usage ----
    int m = t;
    {
        float u0 = pu[b * NM + m];
        float uaw = u0 + (1.f - u0) * pww[b * NM + m];
        float phi = 1.f;
#pragma unroll
        for (int r = 0; r < NR; r++)
            phi *= (1.f - cl_fg[r] * prw[(b * 4 + r) * NM + m]);
        float u = uaw * phi;
        out[OO_USAGE + b * NM + m] = u;
        sv[t] = EPSF + (1.0f - EPSF) * u;
        si[t] = t;
    }
    __syncthreads();

    // ---- Phase C: bitonic sort + product scan + scatter alloc ----
    for (int k = 2; k <= 1024; k <<= 1) {
        for (int j = k >> 1; j > 0; j >>= 1) {
            int ixj = t ^ j;
            if (ixj > t) {
                float a = sv[t], c = sv[ixj];
                int ia = si[t], ic = si[ixj];
                bool asc = (t & k) == 0;
                bool gt = (a > c) || (a == c && ia > ic);
                if (gt == asc) { sv[t] = c; sv[ixj] = a; si[t] = ic; si[ixj] = ia; }
            }
            __syncthreads();
        }
    }
    sp[t] = sv[t];
    __syncthreads();
    for (int off = 1; off < 1024; off <<= 1) {
        float v = sp[t];
        float o = (t >= off) ? sp[t - off] : 1.f;
        __syncthreads();
        sp[t] = v * o;
        __syncthreads();
    }
    {
        float excl = (t == 0) ? 1.f : sp[t - 1];
        swaw[si[t]] = (1.f - sv[t]) * excl;
    }
    __syncthreads();

    // ---- Phase D: write cosine + softmax + ww + precedence ----
    float kn2 = 0.f;
#pragma unroll
    for (int w = 0; w < 64; w++) { float v = cl_wk[w]; kn2 += v * v; }
    float kn = sqrtf(kn2 + EPSF);
    const float* prow = pm + ((size_t)(b * NM + m)) * 64;
    float dot = 0.f, mn2 = 0.f;
    for (int w = 0; w < 64; w++) { float pv = prow[w]; dot += cl_wk[w] * pv; mn2 += pv * pv; }
    float sim = dot / (kn * sqrtf(mn2 + EPSF)) * cl_scal[2];
    red[t] = sim; __syncthreads();
    for (int s = 512; s > 0; s >>= 1) { if (t < s) red[t] = fmaxf(red[t], red[t + s]); __syncthreads(); }
    float mx = red[0]; __syncthreads();
    float e = expf(sim - mx);
    red[t] = e; __syncthreads();
    for (int s = 512; s > 0; s >>= 1) { if (t < s) red[t] += red[t + s]; __syncthreads(); }
    float se = red[0]; __syncthreads();
    float ag = cl_scal[0], wg = cl_scal[1];
    float ww = wg * (ag * swaw[m] + (1.f - ag) * (e / se));
    wsb[O_WWGT + b * NM + m] = ww;
    out[OO_WWGT + b * NM + m] = ww;
    red[t] = ww; __syncthreads();
    for (int s = 512; s > 0; s >>= 1) { if (t < s) red[t] += red[t + s]; __syncthreads(); }
    float wwsum = red[0];
    out[OO_PREC + b * NM + m] = (1.f - wwsum) * pp[b * NM + m] + ww;

    // ---- Phase E: memory update + norms ----
    float s2 = 0.f;
    float* outr = out + OO_MEM + ((size_t)(b * NM + m)) * 64;
    for (int w = 0; w < 64; w++) {
        float val = prow[w] * (1.f - ww * cl_ev[w]) + ww * cl_wv[w];
        outr[w] = val;
        s2 += val * val;
    }
    wsb[O_MN + b * NM + m] = sqrtf(s2 + EPSF);
}

// ================= K2: fused link + fwd + bwd, wave-per-row-strip, nontemporal stream =================
__global__ __launch_bounds__(256) void k_linkfb(
    const float* __restrict__ pl, const float* __restrict__ pp,
    const float* __restrict__ prw, float* __restrict__ wsb, float* __restrict__ out)
{
    int b = blockIdx.x, rg = blockIdx.y;
    int t = threadIdx.x, wave = t >> 6, lane = t & 63;
    const float* wwb = wsb + O_WWGT + b * NM;
    const float* ppb = pp + b * NM;
    const float* rwb = prw + (size_t)b * 4 * NM;
    f4_t wj[4], pj[4], rwc[4][4];
#pragma unroll
    for (int s = 0; s < 4; s++) {
        int c4 = s * 256 + lane * 4;
        wj[s] = *(const f4_t*)(wwb + c4);
        pj[s] = *(const f4_t*)(ppb + c4);
#pragma unroll
        for (int h = 0; h < 4; h++)
            rwc[h][s] = *(const f4_t*)(rwb + h * NM + c4);
    }
    f4_t bacc[4][4];
#pragma unroll
    for (int h = 0; h < 4; h++)
#pragma unroll
        for (int s = 0; s < 4; s++) bacc[h][s] = (f4_t){0.f, 0.f, 0.f, 0.f};

    int rowbase = rg * 64 + wave * 16;
    f4_t vin[4];
    {
        const float* pr0 = pl + ((size_t)(b * NM + rowbase)) * NM;
#pragma unroll
        for (int s = 0; s < 4; s++)
            vin[s] = __builtin_nontemporal_load((const f4_t*)(pr0 + s * 256 + lane * 4));
    }
    for (int rr = 0; rr < 16; rr++) {
        int row = rowbase + rr;
        f4_t vc[4];
#pragma unroll
        for (int s = 0; s < 4; s++) vc[s] = vin[s];
        if (rr < 15) {
            const float* pn = pl + ((size_t)(b * NM + row + 1)) * NM;
#pragma unroll
            for (int s = 0; s < 4; s++)
                vin[s] = __builtin_nontemporal_load((const f4_t*)(pn + s * 256 + lane * 4));
        }
        float wi = wwb[row];
        float rh0 = rwb[0 * NM + row], rh1 = rwb[1 * NM + row];
        float rh2 = rwb[2 * NM + row], rh3 = rwb[3 * NM + row];
        float a = 1.f - wi;
        float* lkrow = out + OO_LINK + ((size_t)(b * NM + row)) * NM;
        float f0 = 0.f, f1 = 0.f, f2 = 0.f, f3 = 0.f;
#pragma unroll
        for (int s = 0; s < 4; s++) {
            int c4 = s * 256 + lane * 4;
            f4_t lv;
            lv.x = (a - wj[s].x) * vc[s].x + wi * pj[s].x; if (row == c4)     lv.x = 0.f;
            lv.y = (a - wj[s].y) * vc[s].y + wi * pj[s].y; if (row == c4 + 1) lv.y = 0.f;
            lv.z = (a - wj[s].z) * vc[s].z + wi * pj[s].z; if (row == c4 + 2) lv.z = 0.f;
            lv.w = (a - wj[s].w) * vc[s].w + wi * pj[s].w; if (row == c4 + 3) lv.w = 0.f;
            __builtin_nontemporal_store(lv, (f4_t*)(lkrow + c4));
            f0 += rwc[0][s].x * lv.x + rwc[0][s].y * lv.y + rwc[0][s].z * lv.z + rwc[0][s].w * lv.w;
            f1 += rwc[1][s].x * lv.x + rwc[1][s].y * lv.y + rwc[1][s].z * lv.z + rwc[1][s].w * lv.w;
            f2 += rwc[2][s].x * lv.x + rwc[2][s].y * lv.y + rwc[2][s].z * lv.z + rwc[2][s].w * lv.w;
            f3 += rwc[3][s].x * lv.x + rwc[3][s].y * lv.y + rwc[3][s].z * lv.z + rwc[3][s].w * lv.w;
            bacc[0][s].x += rh0 * lv.x; bacc[0][s].y += rh0 * lv.y; bacc[0][s].z += rh0 * lv.z; bacc[0][s].w += rh0 * lv.w;
            bacc[1][s].x += rh1 * lv.x; bacc[1][s].y += rh1 * lv.y; bacc[1][s].z += rh1 * lv.z; bacc[1][s].w += rh1 * lv.w;
            bacc[2][s].x += rh2 * lv.x; bacc[2][s].y += rh2 * lv.y; bacc[2][s].z += rh2 * lv.z; bacc[2][s].w += rh2 * lv.w;
            bacc[3][s].x += rh3 * lv.x; bacc[3][s].y += rh3 * lv.y; bacc[3][s].z += rh3 * lv.z; bacc[3][s].w += rh3 * lv.w;
        }
#pragma unroll
        for (int off = 32; off > 0; off >>= 1) {
            f0 += __shfl_down(f0, off); f1 += __shfl_down(f1, off);
            f2 += __shfl_down(f2, off); f3 += __shfl_down(f3, off);
        }
        if (lane == 0) {
            f4_t fv = (f4_t){f0, f1, f2, f3};
            *(f4_t*)(wsb + O_FWD + (size_t)(b * NM + row) * 4) = fv;
        }
    }
    __shared__ float redb[4][1024];
#pragma unroll
    for (int h = 0; h < 4; h++) {
        __syncthreads();
#pragma unroll
        for (int s = 0; s < 4; s++)
            *(f4_t*)(&redb[wave][s * 256 + lane * 4]) = bacc[h][s];
        __syncthreads();
        for (int i = t; i < 1024; i += 256) {
            float sum = redb[0][i] + redb[1][i] + redb[2][i] + redb[3][i];
            wsb[O_BWDP + ((size_t)((b * 16 + rg) * 4 + h)) * NM + i] = sum;
        }
    }
}

// ================= K3: read cosine + softmax + combine (+bred) + read_words =================
// XCD-locality swizzle: launched with blockIdx.x = r*64 + b so the 4 r-blocks of a
// batch land on the same XCD (XCD = blockIdx % 8 = b % 8) and share L2 for the
// memory re-reads. Pure scheduling heuristic — correctness unaffected.
__global__ __launch_bounds__(256) void k_readw(
    float* __restrict__ wsb, float* __restrict__ out)
{
    int b = blockIdx.x & 63, r = blockIdx.x >> 6, t = threadIdx.x;
    int br = b * 4 + r;
    __shared__ float red[256];
    __shared__ float vv[1024];
    __shared__ float red2[4][64];
    const float* rk = wsb + O_RK + (b * 4 + r) * 64;
    float kn2 = 0.f;
#pragma unroll
    for (int w = 0; w < 64; w++) { float v = rk[w]; kn2 += v * v; }
    float kn = sqrtf(kn2 + EPSF);
    float rstr = wsb[O_RSTR + b * 4 + r];
    float sim[4];
#pragma unroll
    for (int k = 0; k < 4; k++) {
        int m = t + k * 256;
        const float* row = out + OO_MEM + ((size_t)(b * NM + m)) * 64;
        float dot = 0.f;
        for (int w = 0; w < 64; w++) dot += rk[w] * row[w];
        sim[k] = dot / (kn * wsb[O_MN + b * NM + m]) * rstr;
    }
    float lm = fmaxf(fmaxf(sim[0], sim[1]), fmaxf(sim[2], sim[3]));
    red[t] = lm; __syncthreads();
    for (int s = 128; s > 0; s >>= 1) { if (t < s) red[t] = fmaxf(red[t], red[t + s]); __syncthreads(); }
    float mx = red[0]; __syncthreads();
    float e[4]; float ls = 0.f;
#pragma unroll
    for (int k = 0; k < 4; k++) { e[k] = expf(sim[k] - mx); ls += e[k]; }
    red[t] = ls; __syncthreads();
    for (int s = 128; s > 0; s >>= 1) { if (t < s) red[t] += red[t + s]; __syncthreads(); }
    float inv = 1.f / red[0];
    float bm = wsb[O_RM + b * 12 + r * 3 + 0];
    float fm = wsb[O_RM + b * 12 + r * 3 + 1];
    float cm = wsb[O_RM + b * 12 + r * 3 + 2];
#pragma unroll
    for (int k = 0; k < 4; k++) {
        int m = t + k * 256;
        float p = e[k] * inv;
        float bw = 0.f;
#pragma unroll
        for (int rg = 0; rg < 16; rg++)
            bw += wsb[O_BWDP + ((size_t)((b * 16 + rg) * 4 + r)) * NM + m];
        float fw = wsb[O_FWD + (size_t)(b * NM + m) * 4 + r];
        float v = cm * p + fm * fw + bm * bw;
        vv[m] = v;
        out[OO_RW + (size_t)br * NM + m] = v;
    }
    __syncthreads();
    int w = t & 63, chunk = t >> 6;
    const float* mem = out + OO_MEM + (size_t)b * NM * 64;
    float acc = 0.f;
    int m0 = chunk * 256;
    for (int m = m0; m < m0 + 256; m++)
        acc += vv[m] * mem[(size_t)m * 64 + w];
    red2[chunk][w] = acc;
    __syncthreads();
    if (t < 64)
        out[OO_RWORDS + br * 64 + t] = red2[0][t] + red2[1][t] + red2[2][t] + red2[3][t];
}

extern "C" void kernel_launch(void* const* d_in, const int* in_sizes, int n_in,
                              void* d_out, int out_size, void* d_ws, size_t ws_size,
                              hipStream_t stream) {
    const float* wv_w = (const float*)d_in[0];  const float* wv_b = (const float*)d_in[1];
    const float* ev_w = (const float*)d_in[2];  const float* ev_b = (const float*)d_in[3];
    const float* fg_w = (const float*)d_in[4];  const float* fg_b = (const float*)d_in[5];
    const float* ag_w = (const float*)d_in[6];  const float* ag_b = (const float*)d_in[7];
    const float* wg_w = (const float*)d_in[8];  const float* wg_b = (const float*)d_in[9];
    const float* rm_w = (const float*)d_in[10]; const float* rm_b = (const float*)d_in[11];
    const float* ws_w = (const float*)d_in[12]; const float* ws_b = (const float*)d_in[13];
    const float* rs_w = (const float*)d_in[14]; const float* rs_b = (const float*)d_in[15];
    const float* wk_w = (const float*)d_in[16]; const float* wk_b = (const float*)d_in[17];
    const float* rk_w = (const float*)d_in[18]; const float* rk_b = (const float*)d_in[19];
    const float* x   = (const float*)d_in[20];
    const float* pm  = (const float*)d_in[21];
    const float* prw = (const float*)d_in[22];
    const float* pww = (const float*)d_in[23];
    const float* pl  = (const float*)d_in[24];
    const float* pp  = (const float*)d_in[25];
    const float* pu  = (const float*)d_in[26];
    float* out = (float*)d_out;
    float* wsb = (float*)d_ws;

    k_front<<<NB, 1024, 0, stream>>>(x, wv_w, wv_b, ev_w, ev_b, fg_w, fg_b, ag_w, ag_b,
                                     wg_w, wg_b, rm_w, rm_b, ws_w, ws_b, rs_w, rs_b,
                                     wk_w, wk_b, rk_w, rk_b,
                                     pm, pp, pu, prw, pww, wsb, out);
    k_linkfb<<<dim3(NB, 16), 256, 0, stream>>>(pl, pp, prw, wsb, out);
    k_readw<<<NB * NR, 256, 0, stream>>>(wsb, out);
}